// Round 3
// baseline (667.099 us; speedup 1.0000x reference)
//
#include <hip/hip_runtime.h>

#define N 8192
#define TT 128                        // tile side
#define TILES (N / TT)                // 64
#define NP (TILES * (TILES + 1) / 2)  // 2080 unordered tile pairs
#define GRID 512                      // persistent blocks (1 resident/CU, LDS-bound)
#define BLOCK 1024
#define SWZ(r) ((r) & 31)             // 16B-slot XOR swizzle per row (32 slots/row)

typedef float nfloat4 __attribute__((ext_vector_type(4)));

// LDS-only barrier: drains ds ops (producer side) but leaves global loads in
// flight across the barrier — unlike __syncthreads() which drains vmcnt(0).
__device__ inline void lds_barrier() {
    asm volatile("s_waitcnt lgkmcnt(0)" ::: "memory");
    __builtin_amdgcn_s_barrier();
}

__device__ inline void decode_pair(int p, int& bi, int& bj) {
    int g = 0, rem = p;
    #pragma unroll 1
    while (rem >= TILES - g) { rem -= TILES - g; g++; }
    bi = g; bj = g + rem;
}

// Issue 8 coalesced float4 loads (A tile + B tile) into registers.
// Each wave instruction covers 2 full 512B rows -> 1KB contiguous.
__device__ inline void issue_loads(const float* __restrict__ adj, int bi, int bj,
                                   bool diag, int t, float4 va[4], float4 vb[4]) {
    #pragma unroll
    for (int k = 0; k < 4; k++) {
        int f = k * BLOCK + t;
        int row = f >> 5, j = f & 31;
        va[k] = *(const float4*)(adj + (size_t)(bi * TT + row) * N + bj * TT + j * 4);
    }
    if (!diag) {
        #pragma unroll
        for (int k = 0; k < 4; k++) {
            int f = k * BLOCK + t;
            int row = f >> 5, j = f & 31;
            vb[k] = *(const float4*)(adj + (size_t)(bj * TT + row) * N + bi * TT + j * 4);
        }
    }
}

// Swizzled LDS stage: element (row, slot j) stored at slot j ^ SWZ(row).
// b128 writes, conflict-free (16 lanes of a quarter-wave hit 16 distinct slots).
__device__ inline void write_stage(int t, const float4 va[4], const float4 vb[4],
                                   float* ldsA, float* ldsB, bool diag) {
    #pragma unroll
    for (int k = 0; k < 4; k++) {
        int f = k * BLOCK + t;
        int row = f >> 5, j = f & 31;
        int off = row * TT + ((j ^ SWZ(row)) << 2);
        *(float4*)(ldsA + off) = va[k];
        if (!diag) *(float4*)(ldsB + off) = vb[k];
    }
}

// Pass 1: rowsum[i] = sum_j max(adj[i][j], adj[j][i]), diagonal forced to 1.
__global__ __launch_bounds__(BLOCK) void k_rowsum(const float* __restrict__ adj,
                                                  float* __restrict__ rowsum) {
    __shared__ float ldsA[TT * TT];
    __shared__ float ldsB[TT * TT];
    __shared__ float red[BLOCK];
    int t = threadIdx.x;
    int r = t & 127;       // row owned for partial sums
    int q = t >> 7;        // col-chunk 0..7 (16 cols each)

    int p = (int)blockIdx.x;
    int bi, bj; decode_pair(p, bi, bj);
    bool diag = (bi == bj);
    float4 va[4], vb[4];
    issue_loads(adj, bi, bj, diag, t, va, vb);

    for (;;) {
        write_stage(t, va, vb, ldsA, ldsB, diag);
        // issue NEXT pair's loads now: they fly across the raw barriers below,
        // hidden under compute + reduction (va/vb free after write_stage).
        int pn = p + GRID;
        bool more = (pn < NP);
        int nbi = 0, nbj = 0; bool ndiag = false;
        if (more) {
            decode_pair(pn, nbi, nbj);
            ndiag = (nbi == nbj);
            issue_loads(adj, nbi, nbj, ndiag, t, va, vb);
        }
        lds_barrier();   // stage visible; global loads stay in flight

        const float* LB = diag ? ldsA : ldsB;
        float rowAcc = 0.f, colAcc = 0.f;
        #pragma unroll
        for (int kk = 0; kk < 4; kk++) {
            int j = q * 4 + kk;
            int roff = r * TT + ((j ^ SWZ(r)) << 2);
            float4 a4 = *(const float4*)(ldsA + roff);          // A[r][c] row-major
            float4 b4 = diag ? a4 : *(const float4*)(ldsB + roff);
            #pragma unroll
            for (int x = 0; x < 4; x++) {
                int c = j * 4 + x;
                int tof = c * TT + (((r >> 2) ^ SWZ(c)) << 2) + (r & 3);
                float a_cr = ldsA[tof];                          // A[c][r]
                float b_cr = LB[tof];                            // B[c][r]
                float m1 = fmaxf(((const float*)&a4)[x], b_cr);  // M[r][c]
                if (diag && r == c) m1 = 1.0f;
                rowAcc += m1;
                if (!diag)                                       // M[c][r] partial for bj rows
                    colAcc += fmaxf(((const float*)&b4)[x], a_cr);
            }
        }
        lds_barrier();   // tile reads done

        // reduction: 8 col-chunk partials per row -> one atomic per row
        red[t] = rowAcc;
        lds_barrier();
        if (t < 128) {
            float s = 0.f;
            #pragma unroll
            for (int qq = 0; qq < 8; qq++) s += red[qq * 128 + t];
            atomicAdd(&rowsum[bi * TT + t], s);
        }
        if (!diag) {
            lds_barrier();           // protect red[] readers
            red[t] = colAcc;
            lds_barrier();
            if (t < 128) {
                float s = 0.f;
                #pragma unroll
                for (int qq = 0; qq < 8; qq++) s += red[qq * 128 + t];
                atomicAdd(&rowsum[bj * TT + t], s);
            }
        }
        if (!more) break;
        p = pn; bi = nbi; bj = nbj; diag = ndiag;
    }
}

// Pass 2: out[i][j] = M[i][j] * rsqrt(rowsum[i]) * rsqrt(rowsum[j])
__global__ __launch_bounds__(BLOCK) void k_scale(const float* __restrict__ adj,
                                                 const float* __restrict__ rowsum,
                                                 float* __restrict__ out) {
    __shared__ float ldsA[TT * TT];
    __shared__ float ldsB[TT * TT];
    __shared__ float dA[TT];
    __shared__ float dB[TT];
    int t = threadIdx.x;

    int p = (int)blockIdx.x;
    int bi, bj; decode_pair(p, bi, bj);
    bool diag = (bi == bj);
    float4 va[4], vb[4];
    float rsv = 0.f;
    issue_loads(adj, bi, bj, diag, t, va, vb);
    if (t < 128)      rsv = rowsum[bi * TT + t];
    else if (t < 256) rsv = rowsum[bj * TT + (t - 128)];

    for (;;) {
        write_stage(t, va, vb, ldsA, ldsB, diag);
        if (t < 128)      dA[t]       = rsqrtf(rsv);
        else if (t < 256) dB[t - 128] = rsqrtf(rsv);
        // issue next pair's loads: fly across barriers, hidden under compute
        int pn = p + GRID;
        bool more = (pn < NP);
        int nbi = 0, nbj = 0; bool ndiag = false;
        if (more) {
            decode_pair(pn, nbi, nbj);
            ndiag = (nbi == nbj);
            issue_loads(adj, nbi, nbj, ndiag, t, va, vb);
            if (t < 128)      rsv = rowsum[nbi * TT + t];
            else if (t < 256) rsv = rowsum[nbj * TT + (t - 128)];
        }
        lds_barrier();

        const float* LB = diag ? ldsA : ldsB;
        #pragma unroll
        for (int k = 0; k < 4; k++) {
            int f = k * BLOCK + t;
            int row = f >> 5, j = f & 31;     // quarter-wave = 256B contiguous stores
            int roff = row * TT + ((j ^ SWZ(row)) << 2);
            float4 a4 = *(const float4*)(ldsA + roff);
            nfloat4 v;
            #pragma unroll
            for (int x = 0; x < 4; x++) {
                int c = j * 4 + x;
                int tof = c * TT + (((row >> 2) ^ SWZ(c)) << 2) + (row & 3);
                float m = fmaxf(((const float*)&a4)[x], LB[tof]);
                if (diag && row == c) m = 1.0f;
                v[x] = m * dA[row] * dB[c];
            }
            __builtin_nontemporal_store(v,
                (nfloat4*)(out + (size_t)(bi * TT + row) * N + bj * TT + j * 4));
            if (!diag) {
                float4 b4 = *(const float4*)(ldsB + roff);
                nfloat4 u;
                #pragma unroll
                for (int x = 0; x < 4; x++) {
                    int c = j * 4 + x;
                    int tof = c * TT + (((row >> 2) ^ SWZ(c)) << 2) + (row & 3);
                    float m = fmaxf(((const float*)&b4)[x], ldsA[tof]);
                    u[x] = m * dB[row] * dA[c];
                }
                __builtin_nontemporal_store(u,
                    (nfloat4*)(out + (size_t)(bj * TT + row) * N + bi * TT + j * 4));
            }
        }
        lds_barrier();   // LDS reads done before next overwrite

        if (!more) break;
        p = pn; bi = nbi; bj = nbj; diag = ndiag;
    }
}

extern "C" void kernel_launch(void* const* d_in, const int* in_sizes, int n_in,
                              void* d_out, int out_size, void* d_ws, size_t ws_size,
                              hipStream_t stream) {
    const float* adj = (const float*)d_in[0];
    float* out = (float*)d_out;
    float* rowsum = (float*)d_ws;   // N floats of scratch

    (void)hipMemsetAsync(rowsum, 0, N * sizeof(float), stream);
    k_rowsum<<<GRID, BLOCK, 0, stream>>>(adj, rowsum);
    k_scale<<<GRID, BLOCK, 0, stream>>>(adj, rowsum, out);
}

// Round 4
// 514.934 us; speedup vs baseline: 1.2955x; 1.2955x over previous
//
#include <hip/hip_runtime.h>

#define N 8192
#define T 64
#define TILES (N / T)              // 128
#define SUP 8                      // tiles per super-tile side (512 floats = 2KB/row span)
#define NSUP (TILES / SUP)         // 16 super-stripes
#define PPB 4                      // tile-pairs per block
#define NBLOCKS 2064               // 120 off-diag supers*16 blocks + 16 diag supers*9 blocks
#define LDS_STRIDE 65              // +1 pad: transposed reads are 2-way (free per m136)
#define BLOCK 512

// Map block -> PPB tile-pairs, grouped into 8x8-tile super-tiles so that
// concurrently-resident blocks touch 2KB-contiguous row spans (DRAM page dense)
// on BOTH the (bi,bj) side and the transposed (bj,bi) side.
// blocks before super-stripe BI: 9*BI + 16*sum_{k<BI}(15-k) = 257*BI - 8*BI*BI
__device__ inline void decode_block(int b, int bis[PPB], int bjs[PPB]) {
    int BI = 0;
    #pragma unroll 1
    while (BI < NSUP - 1) {
        int nb = BI + 1;
        if (257 * nb - 8 * nb * nb <= b) BI = nb; else break;
    }
    int rem = b - (257 * BI - 8 * BI * BI);
    if (rem < 9) {
        // diagonal super-tile: 36 triangular 8x8 pairs; chunk rem covers l=4*rem..+3
        #pragma unroll
        for (int u = 0; u < PPB; u++) {
            int l = 4 * rem + u;
            int i = 0;
            #pragma unroll 1
            while ((i + 1) * 8 - (i + 1) * i / 2 <= l) i++;
            int j = i + (l - (i * 8 - i * (i - 1) / 2));
            bis[u] = BI * SUP + i;
            bjs[u] = BI * SUP + j;
        }
    } else {
        // off-diagonal super (BI, BI+d): 64 pairs, 16 chunks of 4 consecutive bj
        int r2 = rem - 9;
        int d = (r2 >> 4) + 1;
        int q = r2 & 15;
        int i = q >> 1;
        int j0 = (q & 1) * 4;
        #pragma unroll
        for (int u = 0; u < PPB; u++) {
            bis[u] = BI * SUP + i;                 // bi constant within block
            bjs[u] = (BI + d) * SUP + j0 + u;      // 4 consecutive bj tiles
        }
    }
}

// Pass 1: rowsum[i] = sum_j max(adj[i][j], adj[j][i]), diagonal forced to 1.
// Register double-buffered staging: pair k+1's global loads are in flight
// during pair k's compute. bi-side row sums accumulate across same-bi pairs.
__global__ __launch_bounds__(BLOCK) void k_rowsum(const float* __restrict__ adj,
                                                  float* __restrict__ rowsum) {
    __shared__ float ldsA[T * LDS_STRIDE];
    __shared__ float ldsB[T * LDS_STRIDE];
    __shared__ float red[BLOCK];
    int bis[PPB], bjs[PPB];
    decode_block((int)blockIdx.x, bis, bjs);

    int t = threadIdx.x;
    int c4 = t & 15;         // float4 column 0..15
    int r0 = t >> 4;         // row 0..31 (and +32)
    int lane = t & 63;
    int w = t >> 6;          // 0..7

    // prefetch pair 0 into registers
    float4 nA0, nA1, nB0, nB1;
    {
        const float* pa = adj + (size_t)(bis[0] * T + r0) * N + bjs[0] * T + c4 * 4;
        nA0 = *(const float4*)pa;
        nA1 = *(const float4*)(pa + (size_t)32 * N);
        const float* pb = adj + (size_t)(bjs[0] * T + r0) * N + bis[0] * T + c4 * 4;
        nB0 = *(const float4*)pb;
        nB1 = *(const float4*)(pb + (size_t)32 * N);
    }

    float accA = 0.0f;
    #pragma unroll
    for (int k = 0; k < PPB; k++) {
        int bi = bis[k], bj = bjs[k];
        if (k > 0) __syncthreads();          // LDS consumed by previous pair
        {
            float* d0 = ldsA + r0 * LDS_STRIDE + c4 * 4;
            d0[0] = nA0.x; d0[1] = nA0.y; d0[2] = nA0.z; d0[3] = nA0.w;
            float* d1 = ldsA + (r0 + 32) * LDS_STRIDE + c4 * 4;
            d1[0] = nA1.x; d1[1] = nA1.y; d1[2] = nA1.z; d1[3] = nA1.w;
            float* e0 = ldsB + r0 * LDS_STRIDE + c4 * 4;
            e0[0] = nB0.x; e0[1] = nB0.y; e0[2] = nB0.z; e0[3] = nB0.w;
            float* e1 = ldsB + (r0 + 32) * LDS_STRIDE + c4 * 4;
            e1[0] = nB1.x; e1[1] = nB1.y; e1[2] = nB1.z; e1[3] = nB1.w;
        }
        if (k + 1 < PPB) {                   // issue next pair's loads now
            const float* pa = adj + (size_t)(bis[k + 1] * T + r0) * N + bjs[k + 1] * T + c4 * 4;
            nA0 = *(const float4*)pa;
            nA1 = *(const float4*)(pa + (size_t)32 * N);
            const float* pb = adj + (size_t)(bjs[k + 1] * T + r0) * N + bis[k + 1] * T + c4 * 4;
            nB0 = *(const float4*)pb;
            nB1 = *(const float4*)(pb + (size_t)32 * N);
        }
        __syncthreads();

        // bj-side column sums (skip for diagonal tiles: fully counted on bi side)
        if (bi != bj) {
            float acc2 = 0.0f;
            #pragma unroll
            for (int kk = 0; kk < 8; kk++) {
                int r = w * 8 + kk;
                acc2 += fmaxf(ldsA[r * LDS_STRIDE + lane], ldsB[lane * LDS_STRIDE + r]);
            }
            red[t] = acc2;
            __syncthreads();
            if (t < 64) {
                float s = 0.0f;
                #pragma unroll
                for (int w2 = 0; w2 < 8; w2++) s += red[w2 * 64 + t];
                atomicAdd(&rowsum[bj * T + t], s);
            }
        }

        // bi-side row sums: thread owns row=lane, cols w*8..w*8+7; accumulate across pairs
        #pragma unroll
        for (int kk = 0; kk < 8; kk++) {
            int c = w * 8 + kk;
            float m = fmaxf(ldsA[lane * LDS_STRIDE + c], ldsB[c * LDS_STRIDE + lane]);
            if (bi == bj && lane == c) m = 1.0f;   // self-loop
            accA += m;
        }
        bool flush = (k == PPB - 1) || (bis[k + 1] != bi);
        if (flush) {
            __syncthreads();                 // also protects red[] from bj-side readers
            red[t] = accA;
            __syncthreads();
            if (t < 64) {
                float s = 0.0f;
                #pragma unroll
                for (int w2 = 0; w2 < 8; w2++) s += red[w2 * 64 + t];
                atomicAdd(&rowsum[bi * T + t], s);
            }
            accA = 0.0f;
        }
    }
}

// Pass 2: out[i][j] = max'(i,j) * rsqrt(rowsum[i]) * rsqrt(rowsum[j])
// Same super-tile schedule + register double-buffering. Plain (write-back)
// float4 stores: L2 combines them into full 64B lines — non-temporal stores
// measured 1.95x WRITE_SIZE amplification here (R3: 523MB vs 268MB ideal).
__global__ __launch_bounds__(BLOCK) void k_scale(const float* __restrict__ adj,
                                                 const float* __restrict__ rowsum,
                                                 float* __restrict__ out) {
    __shared__ float ldsA[T * LDS_STRIDE];
    __shared__ float ldsB[T * LDS_STRIDE];
    __shared__ float dA[T];
    __shared__ float dB[T];
    int bis[PPB], bjs[PPB];
    decode_block((int)blockIdx.x, bis, bjs);

    int t = threadIdx.x;
    int c4 = t & 15;
    int r0 = t >> 4;         // 0..31

    // prefetch all rowsum slices for this block (tiny, L2/L3-hot)
    float rA[PPB], rB[PPB];
    #pragma unroll
    for (int u = 0; u < PPB; u++) {
        if (t < 64)       rA[u] = rowsum[bis[u] * T + t];
        else if (t < 128) rB[u] = rowsum[bjs[u] * T + (t - 64)];
    }

    // prefetch pair 0 tiles
    float4 nA0, nA1, nB0, nB1;
    {
        const float* pa = adj + (size_t)(bis[0] * T + r0) * N + bjs[0] * T + c4 * 4;
        nA0 = *(const float4*)pa;
        nA1 = *(const float4*)(pa + (size_t)32 * N);
        const float* pb = adj + (size_t)(bjs[0] * T + r0) * N + bis[0] * T + c4 * 4;
        nB0 = *(const float4*)pb;
        nB1 = *(const float4*)(pb + (size_t)32 * N);
    }

    #pragma unroll
    for (int k = 0; k < PPB; k++) {
        int bi = bis[k], bj = bjs[k];
        if (k > 0) __syncthreads();
        {
            float* d0 = ldsA + r0 * LDS_STRIDE + c4 * 4;
            d0[0] = nA0.x; d0[1] = nA0.y; d0[2] = nA0.z; d0[3] = nA0.w;
            float* d1 = ldsA + (r0 + 32) * LDS_STRIDE + c4 * 4;
            d1[0] = nA1.x; d1[1] = nA1.y; d1[2] = nA1.z; d1[3] = nA1.w;
            float* e0 = ldsB + r0 * LDS_STRIDE + c4 * 4;
            e0[0] = nB0.x; e0[1] = nB0.y; e0[2] = nB0.z; e0[3] = nB0.w;
            float* e1 = ldsB + (r0 + 32) * LDS_STRIDE + c4 * 4;
            e1[0] = nB1.x; e1[1] = nB1.y; e1[2] = nB1.z; e1[3] = nB1.w;
        }
        if (t < 64)       dA[t]      = rsqrtf(rA[k]);
        else if (t < 128) dB[t - 64] = rsqrtf(rB[k]);
        if (k + 1 < PPB) {
            const float* pa = adj + (size_t)(bis[k + 1] * T + r0) * N + bjs[k + 1] * T + c4 * 4;
            nA0 = *(const float4*)pa;
            nA1 = *(const float4*)(pa + (size_t)32 * N);
            const float* pb = adj + (size_t)(bjs[k + 1] * T + r0) * N + bis[k + 1] * T + c4 * 4;
            nB0 = *(const float4*)pb;
            nB1 = *(const float4*)(pb + (size_t)32 * N);
        }
        __syncthreads();

        // Upper tile: rows bi*T+rr, cols bj*T+cc — coalesced float4 stores
        #pragma unroll
        for (int rr = r0; rr < T; rr += 32) {
            float4 v;
            float* vp = &v.x;
            #pragma unroll
            for (int kk = 0; kk < 4; kk++) {
                int cc = c4 * 4 + kk;
                float m = fmaxf(ldsA[rr * LDS_STRIDE + cc], ldsB[cc * LDS_STRIDE + rr]);
                if (bi == bj && rr == cc) m = 1.0f;
                vp[kk] = m * dA[rr] * dB[cc];
            }
            *(float4*)(out + (size_t)(bi * T + rr) * N + bj * T + c4 * 4) = v;
        }
        // Mirror tile: rows bj*T+rr, cols bi*T+cc
        if (bi != bj) {
            #pragma unroll
            for (int rr = r0; rr < T; rr += 32) {
                float4 v;
                float* vp = &v.x;
                #pragma unroll
                for (int kk = 0; kk < 4; kk++) {
                    int cc = c4 * 4 + kk;
                    float m = fmaxf(ldsB[rr * LDS_STRIDE + cc], ldsA[cc * LDS_STRIDE + rr]);
                    vp[kk] = m * dB[rr] * dA[cc];
                }
                *(float4*)(out + (size_t)(bj * T + rr) * N + bi * T + c4 * 4) = v;
            }
        }
    }
}

extern "C" void kernel_launch(void* const* d_in, const int* in_sizes, int n_in,
                              void* d_out, int out_size, void* d_ws, size_t ws_size,
                              hipStream_t stream) {
    const float* adj = (const float*)d_in[0];
    float* out = (float*)d_out;
    float* rowsum = (float*)d_ws;   // N floats of scratch

    (void)hipMemsetAsync(rowsum, 0, N * sizeof(float), stream);
    k_rowsum<<<NBLOCKS, BLOCK, 0, stream>>>(adj, rowsum);
    k_scale<<<NBLOCKS, BLOCK, 0, stream>>>(adj, rowsum, out);
}

// Round 5
// 507.604 us; speedup vs baseline: 1.3142x; 1.0144x over previous
//
#include <hip/hip_runtime.h>

#define N 8192
#define T 64
#define TILES (N / T)                      // 128
#define NPAIRS (TILES * (TILES + 1) / 2)   // 8256
#define BLOCK 256

// Decode linear pair index p -> (bi <= bj), upper triangle incl. diagonal.
// (verified in the 500us baseline sessions)
__device__ inline void decode_pair(int p, int& bi, int& bj) {
    float t = (float)TILES + 0.5f;
    int g = (int)(t - sqrtf(t * t - 2.0f * (float)p));
    if (g < 0) g = 0;
    if (g > TILES - 1) g = TILES - 1;
    while (g < TILES - 1 && ((g + 1) * TILES - (g + 1) * g / 2) <= p) g++;
    while (g > 0 && (g * TILES - g * (g - 1) / 2) > p) g--;
    bi = g;
    bj = g + (p - (g * TILES - g * (g - 1) / 2));
}

// Per-thread 4x4 register micro-tile: thread (r4,c4) covers
//   A = adj[bi*64 + 4r4 + x][bj*64 + 4c4 + y]   (4 coalesced float4 row reads)
//   B = adj[bj*64 + 4c4 + y][bi*64 + 4r4 + x]   (4 coalesced float4 row reads)
// so M[r][c] = max(A[r][c], A^T[r][c]) is formed entirely in registers.
// Mapping: c4 = t&15 (fast), r4 = t>>4 -> row-side reduction is intra-wave.

// Pass 1: rowsum[i] = sum_j max(adj[i][j], adj[j][i]), diagonal forced to 1.
__global__ __launch_bounds__(BLOCK) void k_rowsum(const float* __restrict__ adj,
                                                  float* __restrict__ rowsum) {
    __shared__ float red[T * 17];   // col-side partials [c][r4], pad 17 (2-way max)
    int bi, bj;
    decode_pair((int)blockIdx.x, bi, bj);
    bool diag = (bi == bj);
    int t = threadIdx.x;
    int c4 = t & 15, r4 = t >> 4;

    float4 va[4], vb[4];
    const float* pa = adj + (size_t)(bi * T + 4 * r4) * N + bj * T + 4 * c4;
    #pragma unroll
    for (int x = 0; x < 4; x++) va[x] = *(const float4*)(pa + (size_t)x * N);
    const float* pb = adj + (size_t)(bj * T + 4 * c4) * N + bi * T + 4 * r4;
    #pragma unroll
    for (int y = 0; y < 4; y++) vb[y] = *(const float4*)(pb + (size_t)y * N);

    float rowP[4] = {0.f, 0.f, 0.f, 0.f};
    float colP[4] = {0.f, 0.f, 0.f, 0.f};
    #pragma unroll
    for (int x = 0; x < 4; x++) {
        const float* ax = (const float*)&va[x];
        #pragma unroll
        for (int y = 0; y < 4; y++) {
            float b = ((const float*)&vb[y])[x];
            float m = fmaxf(ax[y], b);
            if (diag && (4 * r4 + x == 4 * c4 + y)) m = 1.0f;  // self-loop
            rowP[x] += m;   // contributes to row bi*T + 4r4 + x
            colP[y] += m;   // contributes to row bj*T + 4c4 + y (M symmetric)
        }
    }

    // Row side: reduce over c4 = 16 contiguous lanes (same wave) via butterfly.
    #pragma unroll
    for (int mask = 1; mask <= 8; mask <<= 1) {
        #pragma unroll
        for (int x = 0; x < 4; x++) rowP[x] += __shfl_xor(rowP[x], mask);
    }
    if (c4 < 4) atomicAdd(&rowsum[bi * T + 4 * r4 + c4], rowP[c4]);

    // Col side: reduce over r4 (crosses waves) via small LDS array, one barrier.
    // Diagonal pairs: row side already covers every row of the tile -> skip.
    if (!diag) {
        #pragma unroll
        for (int y = 0; y < 4; y++) red[(4 * c4 + y) * 17 + r4] = colP[y];
        __syncthreads();
        if (t < 64) {
            float s = 0.f;
            #pragma unroll
            for (int k = 0; k < 16; k++) s += red[t * 17 + k];
            atomicAdd(&rowsum[bj * T + t], s);
        }
    }
}

// Pass 2: out[i][j] = M[i][j] * rsqrt(rowsum[i]) * rsqrt(rowsum[j])
// Zero LDS, zero barriers: pure load -> register transpose-max -> store stream.
__global__ __launch_bounds__(BLOCK) void k_scale(const float* __restrict__ adj,
                                                 const float* __restrict__ rowsum,
                                                 float* __restrict__ out) {
    int bi, bj;
    decode_pair((int)blockIdx.x, bi, bj);
    bool diag = (bi == bj);
    int t = threadIdx.x;
    int c4 = t & 15, r4 = t >> 4;

    float4 va[4], vb[4];
    const float* pa = adj + (size_t)(bi * T + 4 * r4) * N + bj * T + 4 * c4;
    #pragma unroll
    for (int x = 0; x < 4; x++) va[x] = *(const float4*)(pa + (size_t)x * N);
    const float* pb = adj + (size_t)(bj * T + 4 * c4) * N + bi * T + 4 * r4;
    #pragma unroll
    for (int y = 0; y < 4; y++) vb[y] = *(const float4*)(pb + (size_t)y * N);

    // rowsum is 32KB and hammered by all blocks -> L1/L2-hot scalar loads.
    float dA[4], dB[4];
    #pragma unroll
    for (int x = 0; x < 4; x++) dA[x] = rsqrtf(rowsum[bi * T + 4 * r4 + x]);
    #pragma unroll
    for (int y = 0; y < 4; y++) dB[y] = rsqrtf(rowsum[bj * T + 4 * c4 + y]);

    float m[4][4];
    #pragma unroll
    for (int x = 0; x < 4; x++) {
        const float* ax = (const float*)&va[x];
        #pragma unroll
        for (int y = 0; y < 4; y++) {
            float b = ((const float*)&vb[y])[x];
            float v = fmaxf(ax[y], b);
            if (diag && (4 * r4 + x == 4 * c4 + y)) v = 1.0f;
            m[x][y] = v;
        }
    }

    // A-side: rows bi*T+4r4+x, cols bj*T+4c4.. — coalesced float4 stores
    float* po = out + (size_t)(bi * T + 4 * r4) * N + bj * T + 4 * c4;
    #pragma unroll
    for (int x = 0; x < 4; x++) {
        float4 v;
        v.x = m[x][0] * dA[x] * dB[0];
        v.y = m[x][1] * dA[x] * dB[1];
        v.z = m[x][2] * dA[x] * dB[2];
        v.w = m[x][3] * dA[x] * dB[3];
        *(float4*)(po + (size_t)x * N) = v;
    }
    // Mirror: rows bj*T+4c4+y, cols bi*T+4r4.. (skip for diag: tile symmetric,
    // fully covered by A-side)
    if (!diag) {
        float* pm = out + (size_t)(bj * T + 4 * c4) * N + bi * T + 4 * r4;
        #pragma unroll
        for (int y = 0; y < 4; y++) {
            float4 u;
            u.x = m[0][y] * dB[y] * dA[0];
            u.y = m[1][y] * dB[y] * dA[1];
            u.z = m[2][y] * dB[y] * dA[2];
            u.w = m[3][y] * dB[y] * dA[3];
            *(float4*)(pm + (size_t)y * N) = u;
        }
    }
}

extern "C" void kernel_launch(void* const* d_in, const int* in_sizes, int n_in,
                              void* d_out, int out_size, void* d_ws, size_t ws_size,
                              hipStream_t stream) {
    const float* adj = (const float*)d_in[0];
    float* out = (float*)d_out;
    float* rowsum = (float*)d_ws;   // N floats of scratch

    (void)hipMemsetAsync(rowsum, 0, N * sizeof(float), stream);
    k_rowsum<<<NPAIRS, BLOCK, 0, stream>>>(adj, rowsum);
    k_scale<<<NPAIRS, BLOCK, 0, stream>>>(adj, rowsum, out);
}

// Round 6
// 501.452 us; speedup vs baseline: 1.3303x; 1.0123x over previous
//
#include <hip/hip_runtime.h>

#define N 8192
#define T 64
#define TILES (N / T)                      // 128
#define NPAIRS (TILES * (TILES + 1) / 2)   // 8256
#define BLOCK 256

typedef float nfloat4 __attribute__((ext_vector_type(4)));

// Decode linear pair index p -> (bi <= bj), upper triangle incl. diagonal.
__device__ inline void decode_pair(int p, int& bi, int& bj) {
    float t = (float)TILES + 0.5f;
    int g = (int)(t - sqrtf(t * t - 2.0f * (float)p));
    if (g < 0) g = 0;
    if (g > TILES - 1) g = TILES - 1;
    while (g < TILES - 1 && ((g + 1) * TILES - (g + 1) * g / 2) <= p) g++;
    while (g > 0 && (g * TILES - g * (g - 1) / 2) > p) g--;
    bi = g;
    bj = g + (p - (g * TILES - g * (g - 1) / 2));
}

// Per-thread 4x4 register micro-tile: thread (r4,c4) covers
//   A = adj[bi*64 + 4r4 + x][bj*64 + 4c4 + y]   (4 coalesced float4 row reads)
//   B = adj[bj*64 + 4c4 + y][bi*64 + 4r4 + x]   (4 coalesced float4 row reads)
// M[r][c] = max(A[r][c], A^T[r][c]) formed entirely in registers.

// Pass 1: partial row sums of M, written atomic-free.
// Block (bi,bj) is the UNIQUE writer of part[bi][bj][0..63] (bi-band rows,
// col-band bj contribution) and part[bj][bi][0..63] (bj-band rows, via
// symmetry of M). Diagonal blocks write part[bi][bi] only (row side covers
// the whole tile). Previous atomicAdd design serialized ~2000 RMWs per
// rowsum cache line across 8 XCDs (~95us of k_rowsum's 170us).
__global__ __launch_bounds__(BLOCK) void k_rowsum(const float* __restrict__ adj,
                                                  float* __restrict__ part) {
    __shared__ float red[T * 17];   // col-side partials [c][r4], pad 17
    int bi, bj;
    decode_pair((int)blockIdx.x, bi, bj);
    bool diag = (bi == bj);
    int t = threadIdx.x;
    int c4 = t & 15, r4 = t >> 4;

    float4 va[4], vb[4];
    const float* pa = adj + (size_t)(bi * T + 4 * r4) * N + bj * T + 4 * c4;
    #pragma unroll
    for (int x = 0; x < 4; x++) va[x] = *(const float4*)(pa + (size_t)x * N);
    const float* pb = adj + (size_t)(bj * T + 4 * c4) * N + bi * T + 4 * r4;
    #pragma unroll
    for (int y = 0; y < 4; y++) vb[y] = *(const float4*)(pb + (size_t)y * N);

    float rowP[4] = {0.f, 0.f, 0.f, 0.f};
    float colP[4] = {0.f, 0.f, 0.f, 0.f};
    #pragma unroll
    for (int x = 0; x < 4; x++) {
        const float* ax = (const float*)&va[x];
        #pragma unroll
        for (int y = 0; y < 4; y++) {
            float b = ((const float*)&vb[y])[x];
            float m = fmaxf(ax[y], b);
            if (diag && (4 * r4 + x == 4 * c4 + y)) m = 1.0f;  // self-loop
            rowP[x] += m;   // row bi*T + 4r4 + x
            colP[y] += m;   // row bj*T + 4c4 + y (M symmetric)
        }
    }

    // Row side: reduce over c4 = 16 contiguous lanes (same wave) via butterfly.
    #pragma unroll
    for (int mask = 1; mask <= 8; mask <<= 1) {
        #pragma unroll
        for (int x = 0; x < 4; x++) rowP[x] += __shfl_xor(rowP[x], mask);
    }
    float* prow = part + ((size_t)bi * TILES + bj) * T;
    if (c4 < 4) prow[4 * r4 + c4] = rowP[c4];

    // Col side: reduce over r4 (crosses waves) via small LDS, one barrier.
    if (!diag) {
        #pragma unroll
        for (int y = 0; y < 4; y++) red[(4 * c4 + y) * 17 + r4] = colP[y];
        __syncthreads();
        if (t < 64) {
            float s = 0.f;
            #pragma unroll
            for (int k = 0; k < 16; k++) s += red[t * 17 + k];
            (part + ((size_t)bj * TILES + bi) * T)[t] = s;
        }
    }
}

// Reduce 128 partials per row -> dinv[i] = rsqrt(rowsum[i]). 4MB read, tiny.
__global__ __launch_bounds__(256) void k_dinv(const float* __restrict__ part,
                                              float* __restrict__ dinv) {
    int i = (int)blockIdx.x * 256 + (int)threadIdx.x;   // grid 32*256 = 8192
    int a = i >> 6, r = i & 63;
    float s = 0.f;
    #pragma unroll 8
    for (int b = 0; b < TILES; b++) s += part[((size_t)a * TILES + b) * T + r];
    dinv[i] = rsqrtf(s);
}

// Pass 2: out[i][j] = M[i][j] * dinv[i] * dinv[j]
// Zero LDS, zero barriers. Non-temporal stores (A/B verified: R2 489us with
// nt vs R4 515us without — nt keeps adj L3-resident for this pass's reads).
__global__ __launch_bounds__(BLOCK) void k_scale(const float* __restrict__ adj,
                                                 const float* __restrict__ dinv,
                                                 float* __restrict__ out) {
    int bi, bj;
    decode_pair((int)blockIdx.x, bi, bj);
    bool diag = (bi == bj);
    int t = threadIdx.x;
    int c4 = t & 15, r4 = t >> 4;

    float4 va[4], vb[4];
    const float* pa = adj + (size_t)(bi * T + 4 * r4) * N + bj * T + 4 * c4;
    #pragma unroll
    for (int x = 0; x < 4; x++) va[x] = *(const float4*)(pa + (size_t)x * N);
    const float* pb = adj + (size_t)(bj * T + 4 * c4) * N + bi * T + 4 * r4;
    #pragma unroll
    for (int y = 0; y < 4; y++) vb[y] = *(const float4*)(pb + (size_t)y * N);

    float dA[4], dB[4];
    #pragma unroll
    for (int x = 0; x < 4; x++) dA[x] = dinv[bi * T + 4 * r4 + x];
    #pragma unroll
    for (int y = 0; y < 4; y++) dB[y] = dinv[bj * T + 4 * c4 + y];

    float m[4][4];
    #pragma unroll
    for (int x = 0; x < 4; x++) {
        const float* ax = (const float*)&va[x];
        #pragma unroll
        for (int y = 0; y < 4; y++) {
            float b = ((const float*)&vb[y])[x];
            float v = fmaxf(ax[y], b);
            if (diag && (4 * r4 + x == 4 * c4 + y)) v = 1.0f;
            m[x][y] = v;
        }
    }

    // A-side: rows bi*T+4r4+x, cols bj*T+4c4.. — coalesced float4 nt-stores
    float* po = out + (size_t)(bi * T + 4 * r4) * N + bj * T + 4 * c4;
    #pragma unroll
    for (int x = 0; x < 4; x++) {
        nfloat4 v;
        v[0] = m[x][0] * dA[x] * dB[0];
        v[1] = m[x][1] * dA[x] * dB[1];
        v[2] = m[x][2] * dA[x] * dB[2];
        v[3] = m[x][3] * dA[x] * dB[3];
        __builtin_nontemporal_store(v, (nfloat4*)(po + (size_t)x * N));
    }
    // Mirror: rows bj*T+4c4+y, cols bi*T+4r4.. (skip for diag)
    if (!diag) {
        float* pm = out + (size_t)(bj * T + 4 * c4) * N + bi * T + 4 * r4;
        #pragma unroll
        for (int y = 0; y < 4; y++) {
            nfloat4 u;
            u[0] = m[0][y] * dB[y] * dA[0];
            u[1] = m[1][y] * dB[y] * dA[1];
            u[2] = m[2][y] * dB[y] * dA[2];
            u[3] = m[3][y] * dB[y] * dA[3];
            __builtin_nontemporal_store(u, (nfloat4*)(pm + (size_t)y * N));
        }
    }
}

extern "C" void kernel_launch(void* const* d_in, const int* in_sizes, int n_in,
                              void* d_out, int out_size, void* d_ws, size_t ws_size,
                              hipStream_t stream) {
    const float* adj = (const float*)d_in[0];
    float* out = (float*)d_out;
    float* part = (float*)d_ws;                         // TILES*TILES*T = 4MB
    float* dinv = part + (size_t)TILES * TILES * T;     // 8192 floats

    // no memset needed: every part[][] slot has exactly one unconditional writer
    k_rowsum<<<NPAIRS, BLOCK, 0, stream>>>(adj, part);
    k_dinv<<<N / 256, 256, 0, stream>>>(part, dinv);
    k_scale<<<NPAIRS, BLOCK, 0, stream>>>(adj, dinv, out);
}